// Round 9
// baseline (842.029 us; speedup 1.0000x reference)
//
#include <hip/hip_runtime.h>
#include <hip/hip_bf16.h>

#define LRELU_SLOPE 0.2f

__device__ __forceinline__ float lrelu(float x) { return x > 0.f ? x : LRELU_SLOPE * x; }

// ---------------- utility kernels ----------------
__global__ void k_zero(int* __restrict__ a, int n) {
    int i = blockIdx.x * blockDim.x + threadIdx.x;
    if (i < n) a[i] = 0;
}

__global__ void k_hist(const int* __restrict__ dst, int* __restrict__ deg, int E) {
    int i = blockIdx.x * blockDim.x + threadIdx.x;
    if (i < E) atomicAdd(&deg[dst[i]], 1);
}

// block-level exclusive scan over 1024 elements; writes per-block totals
__global__ __launch_bounds__(1024) void k_scan1(const int* __restrict__ deg, int* __restrict__ off,
                                                int* __restrict__ bsums, int N) {
    int t = threadIdx.x, b = blockIdx.x;
    int idx = b * 1024 + t;
    int v = (idx < N) ? deg[idx] : 0;
    int lane = t & 63, wid = t >> 6;
    int incl = v;
    #pragma unroll
    for (int d = 1; d < 64; d <<= 1) {
        int u = __shfl_up(incl, d);
        if (lane >= d) incl += u;
    }
    __shared__ int ws[16];
    if (lane == 63) ws[wid] = incl;
    __syncthreads();
    if (wid == 0) {
        int wv = (lane < 16) ? ws[lane] : 0;
        #pragma unroll
        for (int d = 1; d < 16; d <<= 1) {
            int u = __shfl_up(wv, d);
            if (lane >= d) wv += u;
        }
        if (lane < 16) ws[lane] = wv;  // inclusive wave sums
    }
    __syncthreads();
    int woff = (wid > 0) ? ws[wid - 1] : 0;
    if (idx < N) off[idx] = woff + incl - v;  // exclusive within block
    if (t == 0) bsums[b] = ws[15];            // block total
}

// single-block exclusive scan of up to 1024 block sums
__global__ __launch_bounds__(1024) void k_scan2(int* __restrict__ bs, int nb) {
    __shared__ int s[1024];
    int t = threadIdx.x;
    s[t] = (t < nb) ? bs[t] : 0;
    __syncthreads();
    for (int d = 1; d < 1024; d <<= 1) {
        int v = (t >= d) ? s[t - d] : 0;
        __syncthreads();
        s[t] += v;
        __syncthreads();
    }
    if (t < nb) bs[t] = t ? s[t - 1] : 0;
}

__global__ __launch_bounds__(1024) void k_scan3(int* __restrict__ off, const int* __restrict__ bs, int N) {
    int i = blockIdx.x * 1024 + threadIdx.x;
    if (i < N) off[i] += bs[blockIdx.x];
}

__global__ void k_scatter(const int* __restrict__ src, const int* __restrict__ dst,
                          const int* __restrict__ off, int* __restrict__ cur,
                          int* __restrict__ csr, int E) {
    int i = blockIdx.x * blockDim.x + threadIdx.x;
    if (i < E) {
        int d = dst[i];
        int pos = off[d] + atomicAdd(&cur[d], 1);
        csr[pos] = src[i];
    }
}

// ---------------- GEMM: XW = X[N,K] @ W[K,64], fused attention logits ----------------
// COL-PER-LANE, NO LDS (r9). Wave = 16 rows, lane = output column; TLP = N/16
// waves = 6.1 waves/SIMD (fixes r7/r8's structural 1.5 waves/SIMD deficit).
// x read as SAME-ADDRESS global float4 loads (all 64 lanes one address -> one
// L1 transaction, hardware broadcast; this is what r6's LDS broadcast did,
// minus the LDS pipe 2x oversubscription that capped it at 54% VALU).
// W chunk (4 k's) in VGPRs via per-lane coalesced loads, reused across 16 rows.
// Per 4-k body: 4 W + 16 x loads (VMEM, latency hidden by TLP) vs 64 FMA.
// REGISTER-PRESSURE HISTORY (do not regress):
//   r3: __launch_bounds__(256,4) VGPR=64 clamp -> spill -> 2.4 GB scratch.
//   r4: straight-line body -> scheduler clustered all loads -> VGPR=256 spill.
//   r5: sched_barrier(0) did NOT stop the clustering (useless on this compiler).
//   r6: dynamic (unroll-disabled) loop = the only reliable scope bound.
//   r9: body kept at 4 k's so a fully-clustered body (~20 float4 live) stays
//       under the spill line.
template <int K>
__global__ __launch_bounds__(256) void k_gemm(const float* __restrict__ X, const float* __restrict__ W,
                                              const float* __restrict__ a_s, const float* __restrict__ a_d,
                                              float* __restrict__ XW, float* __restrict__ Ssrc,
                                              float* __restrict__ Sdst, int N) {
    int t = threadIdx.x, lane = t & 63, wid = t >> 6;
    int rbase = blockIdx.x * 64 + wid * 16;

    // byte offsets of the wave's 16 rows (32-bit: N*K*4 = 102 MB < 4 GB)
    unsigned voff[16];
    #pragma unroll
    for (int r = 0; r < 16; r++) {
        int row = rbase + r;
        row = row < N ? row : N - 1;  // clamp: loads only, no OOB write
        voff[r] = (unsigned)row * (unsigned)(K * 4);
    }

    float acc[16];
    #pragma unroll
    for (int r = 0; r < 16; r++) acc[r] = 0.f;

    // dynamic loop = scheduling-scope bound (r6 lesson)
    #pragma clang loop unroll(disable)
    for (int kh = 0; kh < K; kh += 4) {
        const float* Wk = W + (size_t)kh * 64 + lane;   // lane=col -> coalesced
        const char* Xk = (const char*)(X + kh);         // uniform base, advances with kh
        float w0 = Wk[0], w1 = Wk[64], w2 = Wk[128], w3 = Wk[192];
        #pragma unroll
        for (int q = 0; q < 4; q++) {
            float4 x0 = *(const float4*)(Xk + voff[q * 4 + 0]);  // broadcast loads
            float4 x1 = *(const float4*)(Xk + voff[q * 4 + 1]);
            float4 x2 = *(const float4*)(Xk + voff[q * 4 + 2]);
            float4 x3 = *(const float4*)(Xk + voff[q * 4 + 3]);
            acc[q * 4 + 0] += x0.x * w0; acc[q * 4 + 1] += x1.x * w0;
            acc[q * 4 + 2] += x2.x * w0; acc[q * 4 + 3] += x3.x * w0;
            acc[q * 4 + 0] += x0.y * w1; acc[q * 4 + 1] += x1.y * w1;
            acc[q * 4 + 2] += x2.y * w1; acc[q * 4 + 3] += x3.y * w1;
            acc[q * 4 + 0] += x0.z * w2; acc[q * 4 + 1] += x1.z * w2;
            acc[q * 4 + 2] += x2.z * w2; acc[q * 4 + 3] += x3.z * w2;
            acc[q * 4 + 0] += x0.w * w3; acc[q * 4 + 1] += x1.w * w3;
            acc[q * 4 + 2] += x2.w * w3; acc[q * 4 + 3] += x3.w * w3;
        }
    }

    // epilogue: write XW rows + attention logit reductions
    float as = a_s[lane], ad = a_d[lane];
    #pragma unroll
    for (int r = 0; r < 16; r++) {
        int row = rbase + r;
        if (row < N) {
            XW[(size_t)row * 64 + lane] = acc[r];
            float vs = acc[r] * as, vd = acc[r] * ad;
            #pragma unroll
            for (int d = 32; d > 0; d >>= 1) {
                vs += __shfl_xor(vs, d);
                vd += __shfl_xor(vd, d);
            }
            if (lane == 0) { Ssrc[row] = vs; Sdst[row] = vd; }
        }
    }
}

// ---------------- attention + aggregate: one wave per dst node ----------------
__global__ __launch_bounds__(256) void k_attn(const float* __restrict__ XW, const float* __restrict__ Ssrc,
                                              const float* __restrict__ Sdst, const int* __restrict__ csr,
                                              const int* __restrict__ off, const int* __restrict__ deg,
                                              const float* __restrict__ bias, float* __restrict__ H,
                                              int N, int do_relu) {
    int t = threadIdx.x, lane = t & 63, wid = t >> 6;
    int n = blockIdx.x * 4 + wid;
    if (n >= N) return;
    float sd = Sdst[n];
    int st = off[n], d = deg[n];

    // phase 1: max over edges (lanes parallel over edges); cache first 64 src/e in regs
    float eself = lrelu(Ssrc[n] + sd);
    float m = eself;
    int myS = 0;
    float myE = -1e30f;
    if (lane < d) {
        myS = csr[st + lane];
        myE = lrelu(Ssrc[myS] + sd);
        m = fmaxf(m, myE);
    }
    for (int i = 64 + lane; i < d; i += 64) {
        int s = csr[st + i];
        m = fmaxf(m, lrelu(Ssrc[s] + sd));
    }
    #pragma unroll
    for (int dd = 32; dd > 0; dd >>= 1) m = fmaxf(m, __shfl_xor(m, dd));

    // phase 2: serial over edges, lanes = feature dims
    float w0 = __expf(eself - m);
    float denom = w0;
    float acc = w0 * XW[(size_t)n * 64 + lane];
    int dcap = d < 64 ? d : 64;
    for (int i = 0; i < dcap; i++) {
        int s = __shfl(myS, i);
        float e = __shfl(myE, i);
        float w = __expf(e - m);
        denom += w;
        acc += w * XW[(size_t)s * 64 + lane];
    }
    for (int i = 64; i < d; i++) {
        int s = csr[st + i];
        float e = lrelu(Ssrc[s] + sd);
        float w = __expf(e - m);
        denom += w;
        acc += w * XW[(size_t)s * 64 + lane];
    }
    float o = acc / denom + bias[lane];
    if (do_relu) o = fmaxf(o, 0.f);
    H[(size_t)n * 64 + lane] = o;
}

// ---------------- head: out[i] = [h[u]; h[m]] . fcW + fcb ----------------
__global__ __launch_bounds__(256) void k_head(const float* __restrict__ H, const int* __restrict__ ui,
                                              const int* __restrict__ mi, const float* __restrict__ fcW,
                                              const float* __restrict__ fcb, float* __restrict__ out, int B) {
    int t = threadIdx.x, lane = t & 63, wid = t >> 6;
    int i = blockIdx.x * 4 + wid;
    if (i >= B) return;
    int u = ui[i], m = mi[i];
    float v = H[(size_t)u * 64 + lane] * fcW[lane] + H[(size_t)m * 64 + lane] * fcW[64 + lane];
    #pragma unroll
    for (int dd = 32; dd > 0; dd >>= 1) v += __shfl_xor(v, dd);
    if (lane == 0) out[i] = v + fcb[0];
}

extern "C" void kernel_launch(void* const* d_in, const int* in_sizes, int n_in,
                              void* d_out, int out_size, void* d_ws, size_t ws_size,
                              hipStream_t stream) {
    const float* x   = (const float*)d_in[0];
    const int*   ei  = (const int*)d_in[1];
    const int*   ui  = (const int*)d_in[2];
    const int*   mi  = (const int*)d_in[3];
    const float* W1  = (const float*)d_in[4];
    const float* as1 = (const float*)d_in[5];
    const float* ad1 = (const float*)d_in[6];
    const float* b1  = (const float*)d_in[7];
    const float* W2  = (const float*)d_in[8];
    const float* as2 = (const float*)d_in[9];
    const float* ad2 = (const float*)d_in[10];
    const float* b2  = (const float*)d_in[11];
    const float* fcW = (const float*)d_in[12];
    const float* fcb = (const float*)d_in[13];
    float* out = (float*)d_out;

    const int Hdim = in_sizes[5];            // 64
    const int FIN  = in_sizes[4] / Hdim;     // 256
    const int N    = in_sizes[0] / FIN;      // 100000
    const int E    = in_sizes[1] / 2;        // 1000000
    const int B    = in_sizes[2];            // 16384

    // workspace carve
    char* w = (char*)d_ws;
    auto alloc = [&](size_t bytes) -> void* {
        void* p = (void*)w;
        w += (bytes + 255) & ~(size_t)255;
        return p;
    };
    float* xw   = (float*)alloc((size_t)N * 64 * 4);
    float* hbuf = (float*)alloc((size_t)N * 64 * 4);
    float* ssrc = (float*)alloc((size_t)N * 4);
    float* sdst = (float*)alloc((size_t)N * 4);
    int* degcur = (int*)alloc((size_t)2 * N * 4);  // deg | cur contiguous
    int* deg = degcur;
    int* cur = degcur + N;
    int* offv  = (int*)alloc((size_t)N * 4);
    int* bsums = (int*)alloc((size_t)1024 * 4);
    int* csr   = (int*)alloc((size_t)E * 4);

    const int* esrc = ei;
    const int* edst = ei + E;

    // --- build CSR by dst (shared by both layers) ---
    k_zero<<<(2 * N + 1023) / 1024, 1024, 0, stream>>>(degcur, 2 * N);
    k_hist<<<(E + 255) / 256, 256, 0, stream>>>(edst, deg, E);
    int nb = (N + 1023) / 1024;
    k_scan1<<<nb, 1024, 0, stream>>>(deg, offv, bsums, N);
    k_scan2<<<1, 1024, 0, stream>>>(bsums, nb);
    k_scan3<<<nb, 1024, 0, stream>>>(offv, bsums, N);
    k_scatter<<<(E + 255) / 256, 256, 0, stream>>>(esrc, edst, offv, cur, csr, E);

    const int gemmBlocks = (N + 63) / 64;

    // --- layer 1 ---
    k_gemm<256><<<gemmBlocks, 256, 0, stream>>>(x, W1, as1, ad1, xw, ssrc, sdst, N);
    k_attn<<<(N + 3) / 4, 256, 0, stream>>>(xw, ssrc, sdst, csr, offv, deg, b1, hbuf, N, 1);

    // --- layer 2 (xw buffer reused) ---
    k_gemm<64><<<gemmBlocks, 256, 0, stream>>>(hbuf, W2, as2, ad2, xw, ssrc, sdst, N);
    k_attn<<<(N + 3) / 4, 256, 0, stream>>>(xw, ssrc, sdst, csr, offv, deg, b2, hbuf, N, 0);

    // --- head ---
    k_head<<<(B + 3) / 4, 256, 0, stream>>>(hbuf, ui, mi, fcW, fcb, out, B);
}

// Round 10
// 475.400 us; speedup vs baseline: 1.7712x; 1.7712x over previous
//
#include <hip/hip_runtime.h>
#include <hip/hip_bf16.h>

#define LRELU_SLOPE 0.2f

__device__ __forceinline__ float lrelu(float x) { return x > 0.f ? x : LRELU_SLOPE * x; }

typedef __attribute__((ext_vector_type(8))) short short8;
typedef __attribute__((ext_vector_type(4))) float f32x4;

__device__ __forceinline__ unsigned short f2bf(float f) {
    unsigned u = __builtin_bit_cast(unsigned, f);
    u = (u + 0x7FFFu + ((u >> 16) & 1u)) >> 16;  // RNE
    return (unsigned short)u;
}
__device__ __forceinline__ float bf2f(unsigned short b) {
    unsigned u = ((unsigned)b) << 16;
    return __builtin_bit_cast(float, u);
}

// ---------------- utility kernels ----------------
__global__ void k_zero(int* __restrict__ a, int n) {
    int i = blockIdx.x * blockDim.x + threadIdx.x;
    if (i < n) a[i] = 0;
}

__global__ void k_hist(const int* __restrict__ dst, int* __restrict__ deg, int E) {
    int i = blockIdx.x * blockDim.x + threadIdx.x;
    if (i < E) atomicAdd(&deg[dst[i]], 1);
}

__global__ __launch_bounds__(1024) void k_scan1(const int* __restrict__ deg, int* __restrict__ off,
                                                int* __restrict__ bsums, int N) {
    int t = threadIdx.x, b = blockIdx.x;
    int idx = b * 1024 + t;
    int v = (idx < N) ? deg[idx] : 0;
    int lane = t & 63, wid = t >> 6;
    int incl = v;
    #pragma unroll
    for (int d = 1; d < 64; d <<= 1) {
        int u = __shfl_up(incl, d);
        if (lane >= d) incl += u;
    }
    __shared__ int ws[16];
    if (lane == 63) ws[wid] = incl;
    __syncthreads();
    if (wid == 0) {
        int wv = (lane < 16) ? ws[lane] : 0;
        #pragma unroll
        for (int d = 1; d < 16; d <<= 1) {
            int u = __shfl_up(wv, d);
            if (lane >= d) wv += u;
        }
        if (lane < 16) ws[lane] = wv;
    }
    __syncthreads();
    int woff = (wid > 0) ? ws[wid - 1] : 0;
    if (idx < N) off[idx] = woff + incl - v;
    if (t == 0) bsums[b] = ws[15];
}

__global__ __launch_bounds__(1024) void k_scan2(int* __restrict__ bs, int nb) {
    __shared__ int s[1024];
    int t = threadIdx.x;
    s[t] = (t < nb) ? bs[t] : 0;
    __syncthreads();
    for (int d = 1; d < 1024; d <<= 1) {
        int v = (t >= d) ? s[t - d] : 0;
        __syncthreads();
        s[t] += v;
        __syncthreads();
    }
    if (t < nb) bs[t] = t ? s[t - 1] : 0;
}

__global__ __launch_bounds__(1024) void k_scan3(int* __restrict__ off, const int* __restrict__ bs, int N) {
    int i = blockIdx.x * 1024 + threadIdx.x;
    if (i < N) off[i] += bs[blockIdx.x];
}

__global__ void k_scatter(const int* __restrict__ src, const int* __restrict__ dst,
                          const int* __restrict__ off, int* __restrict__ cur,
                          int* __restrict__ csr, int E) {
    int i = blockIdx.x * blockDim.x + threadIdx.x;
    if (i < E) {
        int d = dst[i];
        int pos = off[d] + atomicAdd(&cur[d], 1);
        csr[pos] = src[i];
    }
}

// ---------------- W pre-pack: fp32 [K][64] -> B-fragment bf16 hi/lo ----------------
// B-frag layout for mfma_f32_16x16x32_bf16: lane supplies B[k=quad*8+j][n=lane&15];
// packed index [(ct*NKC+kc)*64 + lane]*8 + j so the kernel loads one 16B short8/lane.
template <int K>
__global__ __launch_bounds__(256) void k_packW(const float* __restrict__ W,
                                               unsigned short* __restrict__ Bhi,
                                               unsigned short* __restrict__ Blo) {
    constexpr int NKC = K / 32;
    int g = blockIdx.x * 256 + threadIdx.x;
    if (g >= 4 * NKC * 64) return;
    int lane = g & 63;
    int kc = (g >> 6) % NKC;
    int ct = g / (64 * NKC);
    int qd = lane >> 4, col = lane & 15;
    #pragma unroll
    for (int j = 0; j < 8; j++) {
        int k = kc * 32 + qd * 8 + j;
        float w = W[(size_t)k * 64 + ct * 16 + col];
        unsigned short h = f2bf(w);
        float rem = w - bf2f(h);
        Bhi[(size_t)g * 8 + j] = h;
        Blo[(size_t)g * 8 + j] = f2bf(rem);
    }
}

// ---------------- MFMA GEMM: XW = X[N,K] @ W[K,64] + fused logits ----------------
// r10: exit the fp32 issue-pipe regime (r6 LDS 12cyc/b128, r9 TA 16cyc/VMEM both
// plateau ~100-130us). Split-precision bf16: A = X hi+lo converted in-register
// from the fp32 load; B = W hi/lo pre-packed. 3 MFMAs (AhBh+AlBh+AhBl) => ~16-bit
// effective mantissa, absmax ~1e-4 (threshold 1.2e-2).
// A-frag: lane holds A[m=lane&15][k=quad*8+j] -> one row, 8 consecutive k = 32B fp32.
// C/D: col=lane&15, row=quad*4+reg (m89-verified). Logits from fp32 acc in epilogue.
// REGISTER-PRESSURE HISTORY (do not regress):
//   r3 launch_bounds clamp spill / r4 straight-line load-clustering spill /
//   r5 sched_barrier useless / r6 dynamic loop = only reliable scope bound.
template <int K>
__global__ __launch_bounds__(256) void k_mfma(const float* __restrict__ X,
                                              const unsigned short* __restrict__ Bhi,
                                              const unsigned short* __restrict__ Blo,
                                              const float* __restrict__ a_s, const float* __restrict__ a_d,
                                              float* __restrict__ XW, float* __restrict__ Ssrc,
                                              float* __restrict__ Sdst, int N) {
    constexpr int NKC = K / 32;
    int t = threadIdx.x, lane = t & 63, wid = t >> 6;
    int mtile = blockIdx.x * 4 + wid;
    if (mtile * 16 >= N) return;
    int m0 = mtile * 16;
    int qd = lane >> 4, col = lane & 15;

    int rA = m0 + col;
    rA = rA < N ? rA : N - 1;  // load clamp (stores guarded)
    const float* xrow = X + (size_t)rA * K + qd * 8;

    const short8* bh = (const short8*)Bhi;
    const short8* bl = (const short8*)Blo;

    f32x4 acc[4];
    #pragma unroll
    for (int ct = 0; ct < 4; ct++) acc[ct] = (f32x4){0.f, 0.f, 0.f, 0.f};

    // dynamic kc loop = scheduling-scope bound (r6 lesson)
    #pragma clang loop unroll(disable)
    for (int kc = 0; kc < NKC; kc++) {
        const float* xp = xrow + kc * 32;
        float4 xa = *(const float4*)xp;
        float4 xb = *(const float4*)(xp + 4);
        float xv[8] = {xa.x, xa.y, xa.z, xa.w, xb.x, xb.y, xb.z, xb.w};
        short8 ah, al;
        #pragma unroll
        for (int j = 0; j < 8; j++) {
            unsigned short h = f2bf(xv[j]);
            ah[j] = (short)h;
            al[j] = (short)f2bf(xv[j] - bf2f(h));
        }
        #pragma unroll
        for (int ct = 0; ct < 4; ct++) {
            short8 wh = bh[(ct * NKC + kc) * 64 + lane];
            short8 wl = bl[(ct * NKC + kc) * 64 + lane];
            acc[ct] = __builtin_amdgcn_mfma_f32_16x16x32_bf16(ah, wh, acc[ct], 0, 0, 0);
            acc[ct] = __builtin_amdgcn_mfma_f32_16x16x32_bf16(al, wh, acc[ct], 0, 0, 0);
            acc[ct] = __builtin_amdgcn_mfma_f32_16x16x32_bf16(ah, wl, acc[ct], 0, 0, 0);
        }
    }

    // epilogue: store XW + logits (reduce across the 16 lanes of each quad)
    float asx[4], adx[4];
    #pragma unroll
    for (int ct = 0; ct < 4; ct++) {
        asx[ct] = a_s[ct * 16 + col];
        adx[ct] = a_d[ct * 16 + col];
    }
    #pragma unroll
    for (int r = 0; r < 4; r++) {
        int row = m0 + qd * 4 + r;
        if (row < N) {
            float vs = 0.f, vd = 0.f;
            #pragma unroll
            for (int ct = 0; ct < 4; ct++) {
                float v = acc[ct][r];
                XW[(size_t)row * 64 + ct * 16 + col] = v;
                vs += v * asx[ct];
                vd += v * adx[ct];
            }
            #pragma unroll
            for (int d = 1; d < 16; d <<= 1) {
                vs += __shfl_xor(vs, d);
                vd += __shfl_xor(vd, d);
            }
            if (col == 0) { Ssrc[row] = vs; Sdst[row] = vd; }
        }
    }
}

// ---------------- attention + aggregate: one wave per dst node ----------------
__global__ __launch_bounds__(256) void k_attn(const float* __restrict__ XW, const float* __restrict__ Ssrc,
                                              const float* __restrict__ Sdst, const int* __restrict__ csr,
                                              const int* __restrict__ off, const int* __restrict__ deg,
                                              const float* __restrict__ bias, float* __restrict__ H,
                                              int N, int do_relu) {
    int t = threadIdx.x, lane = t & 63, wid = t >> 6;
    int n = blockIdx.x * 4 + wid;
    if (n >= N) return;
    float sd = Sdst[n];
    int st = off[n], d = deg[n];

    float eself = lrelu(Ssrc[n] + sd);
    float m = eself;
    int myS = 0;
    float myE = -1e30f;
    if (lane < d) {
        myS = csr[st + lane];
        myE = lrelu(Ssrc[myS] + sd);
        m = fmaxf(m, myE);
    }
    for (int i = 64 + lane; i < d; i += 64) {
        int s = csr[st + i];
        m = fmaxf(m, lrelu(Ssrc[s] + sd));
    }
    #pragma unroll
    for (int dd = 32; dd > 0; dd >>= 1) m = fmaxf(m, __shfl_xor(m, dd));

    float w0 = __expf(eself - m);
    float denom = w0;
    float acc = w0 * XW[(size_t)n * 64 + lane];
    int dcap = d < 64 ? d : 64;
    for (int i = 0; i < dcap; i++) {
        int s = __shfl(myS, i);
        float e = __shfl(myE, i);
        float w = __expf(e - m);
        denom += w;
        acc += w * XW[(size_t)s * 64 + lane];
    }
    for (int i = 64; i < d; i++) {
        int s = csr[st + i];
        float e = lrelu(Ssrc[s] + sd);
        float w = __expf(e - m);
        denom += w;
        acc += w * XW[(size_t)s * 64 + lane];
    }
    float o = acc / denom + bias[lane];
    if (do_relu) o = fmaxf(o, 0.f);
    H[(size_t)n * 64 + lane] = o;
}

// ---------------- head ----------------
__global__ __launch_bounds__(256) void k_head(const float* __restrict__ H, const int* __restrict__ ui,
                                              const int* __restrict__ mi, const float* __restrict__ fcW,
                                              const float* __restrict__ fcb, float* __restrict__ out, int B) {
    int t = threadIdx.x, lane = t & 63, wid = t >> 6;
    int i = blockIdx.x * 4 + wid;
    if (i >= B) return;
    int u = ui[i], m = mi[i];
    float v = H[(size_t)u * 64 + lane] * fcW[lane] + H[(size_t)m * 64 + lane] * fcW[64 + lane];
    #pragma unroll
    for (int dd = 32; dd > 0; dd >>= 1) v += __shfl_xor(v, dd);
    if (lane == 0) out[i] = v + fcb[0];
}

extern "C" void kernel_launch(void* const* d_in, const int* in_sizes, int n_in,
                              void* d_out, int out_size, void* d_ws, size_t ws_size,
                              hipStream_t stream) {
    const float* x   = (const float*)d_in[0];
    const int*   ei  = (const int*)d_in[1];
    const int*   ui  = (const int*)d_in[2];
    const int*   mi  = (const int*)d_in[3];
    const float* W1  = (const float*)d_in[4];
    const float* as1 = (const float*)d_in[5];
    const float* ad1 = (const float*)d_in[6];
    const float* b1  = (const float*)d_in[7];
    const float* W2  = (const float*)d_in[8];
    const float* as2 = (const float*)d_in[9];
    const float* ad2 = (const float*)d_in[10];
    const float* b2  = (const float*)d_in[11];
    const float* fcW = (const float*)d_in[12];
    const float* fcb = (const float*)d_in[13];
    float* out = (float*)d_out;

    const int Hdim = in_sizes[5];            // 64
    const int FIN  = in_sizes[4] / Hdim;     // 256
    const int N    = in_sizes[0] / FIN;      // 100000
    const int E    = in_sizes[1] / 2;        // 1000000
    const int B    = in_sizes[2];            // 16384

    char* w = (char*)d_ws;
    auto alloc = [&](size_t bytes) -> void* {
        void* p = (void*)w;
        w += (bytes + 255) & ~(size_t)255;
        return p;
    };
    float* xw   = (float*)alloc((size_t)N * 64 * 4);
    float* hbuf = (float*)alloc((size_t)N * 64 * 4);
    float* ssrc = (float*)alloc((size_t)N * 4);
    float* sdst = (float*)alloc((size_t)N * 4);
    int* degcur = (int*)alloc((size_t)2 * N * 4);
    int* deg = degcur;
    int* cur = degcur + N;
    int* offv  = (int*)alloc((size_t)N * 4);
    int* bsums = (int*)alloc((size_t)1024 * 4);
    int* csr   = (int*)alloc((size_t)E * 4);
    unsigned short* b1hi = (unsigned short*)alloc((size_t)4 * 8 * 64 * 8 * 2);
    unsigned short* b1lo = (unsigned short*)alloc((size_t)4 * 8 * 64 * 8 * 2);
    unsigned short* b2hi = (unsigned short*)alloc((size_t)4 * 2 * 64 * 8 * 2);
    unsigned short* b2lo = (unsigned short*)alloc((size_t)4 * 2 * 64 * 8 * 2);

    const int* esrc = ei;
    const int* edst = ei + E;

    // --- W pre-pack (independent of CSR) ---
    k_packW<256><<<8, 256, 0, stream>>>(W1, b1hi, b1lo);
    k_packW<64><<<2, 256, 0, stream>>>(W2, b2hi, b2lo);

    // --- build CSR by dst (shared by both layers) ---
    k_zero<<<(2 * N + 1023) / 1024, 1024, 0, stream>>>(degcur, 2 * N);
    k_hist<<<(E + 255) / 256, 256, 0, stream>>>(edst, deg, E);
    int nb = (N + 1023) / 1024;
    k_scan1<<<nb, 1024, 0, stream>>>(deg, offv, bsums, N);
    k_scan2<<<1, 1024, 0, stream>>>(bsums, nb);
    k_scan3<<<nb, 1024, 0, stream>>>(offv, bsums, N);
    k_scatter<<<(E + 255) / 256, 256, 0, stream>>>(esrc, edst, offv, cur, csr, E);

    const int mfmaBlocks = ((N + 15) / 16 + 3) / 4;

    // --- layer 1 ---
    k_mfma<256><<<mfmaBlocks, 256, 0, stream>>>(x, b1hi, b1lo, as1, ad1, xw, ssrc, sdst, N);
    k_attn<<<(N + 3) / 4, 256, 0, stream>>>(xw, ssrc, sdst, csr, offv, deg, b1, hbuf, N, 1);

    // --- layer 2 ---
    k_mfma<64><<<mfmaBlocks, 256, 0, stream>>>(hbuf, b2hi, b2lo, as2, ad2, xw, ssrc, sdst, N);
    k_attn<<<(N + 3) / 4, 256, 0, stream>>>(xw, ssrc, sdst, csr, offv, deg, b2, hbuf, N, 0);

    // --- head ---
    k_head<<<(B + 3) / 4, 256, 0, stream>>>(hbuf, ui, mi, fcW, fcb, out, B);
}

// Round 11
// 426.362 us; speedup vs baseline: 1.9749x; 1.1150x over previous
//
#include <hip/hip_runtime.h>
#include <hip/hip_bf16.h>

#define LRELU_SLOPE 0.2f

__device__ __forceinline__ float lrelu(float x) { return x > 0.f ? x : LRELU_SLOPE * x; }

typedef __attribute__((ext_vector_type(8))) short short8;
typedef __attribute__((ext_vector_type(4))) float f32x4;

__device__ __forceinline__ unsigned short f2bf(float f) {
    unsigned u = __builtin_bit_cast(unsigned, f);
    u = (u + 0x7FFFu + ((u >> 16) & 1u)) >> 16;  // RNE
    return (unsigned short)u;
}
__device__ __forceinline__ float bf2f(unsigned short b) {
    unsigned u = ((unsigned)b) << 16;
    return __builtin_bit_cast(float, u);
}

// ---------------- utility kernels ----------------
__global__ void k_zero(int* __restrict__ a, int n) {
    int i = blockIdx.x * blockDim.x + threadIdx.x;
    if (i < n) a[i] = 0;
}

__global__ void k_hist(const int* __restrict__ dst, int* __restrict__ deg, int E) {
    int i = blockIdx.x * blockDim.x + threadIdx.x;
    if (i < E) atomicAdd(&deg[dst[i]], 1);
}

__global__ __launch_bounds__(1024) void k_scan1(const int* __restrict__ deg, int* __restrict__ off,
                                                int* __restrict__ bsums, int N) {
    int t = threadIdx.x, b = blockIdx.x;
    int idx = b * 1024 + t;
    int v = (idx < N) ? deg[idx] : 0;
    int lane = t & 63, wid = t >> 6;
    int incl = v;
    #pragma unroll
    for (int d = 1; d < 64; d <<= 1) {
        int u = __shfl_up(incl, d);
        if (lane >= d) incl += u;
    }
    __shared__ int ws[16];
    if (lane == 63) ws[wid] = incl;
    __syncthreads();
    if (wid == 0) {
        int wv = (lane < 16) ? ws[lane] : 0;
        #pragma unroll
        for (int d = 1; d < 16; d <<= 1) {
            int u = __shfl_up(wv, d);
            if (lane >= d) wv += u;
        }
        if (lane < 16) ws[lane] = wv;
    }
    __syncthreads();
    int woff = (wid > 0) ? ws[wid - 1] : 0;
    if (idx < N) off[idx] = woff + incl - v;
    if (t == 0) bsums[b] = ws[15];
}

__global__ __launch_bounds__(1024) void k_scan2(int* __restrict__ bs, int nb) {
    __shared__ int s[1024];
    int t = threadIdx.x;
    s[t] = (t < nb) ? bs[t] : 0;
    __syncthreads();
    for (int d = 1; d < 1024; d <<= 1) {
        int v = (t >= d) ? s[t - d] : 0;
        __syncthreads();
        s[t] += v;
        __syncthreads();
    }
    if (t < nb) bs[t] = t ? s[t - 1] : 0;
}

__global__ __launch_bounds__(1024) void k_scan3(int* __restrict__ off, const int* __restrict__ bs, int N) {
    int i = blockIdx.x * 1024 + threadIdx.x;
    if (i < N) off[i] += bs[blockIdx.x];
}

__global__ void k_scatter(const int* __restrict__ src, const int* __restrict__ dst,
                          const int* __restrict__ off, int* __restrict__ cur,
                          int* __restrict__ csr, int E) {
    int i = blockIdx.x * blockDim.x + threadIdx.x;
    if (i < E) {
        int d = dst[i];
        int pos = off[d] + atomicAdd(&cur[d], 1);
        csr[pos] = src[i];
    }
}

// ---------------- W pre-pack: fp32 [K][64] -> B-fragment bf16 hi/lo ----------------
template <int K>
__global__ __launch_bounds__(256) void k_packW(const float* __restrict__ W,
                                               unsigned short* __restrict__ Bhi,
                                               unsigned short* __restrict__ Blo) {
    constexpr int NKC = K / 32;
    int g = blockIdx.x * 256 + threadIdx.x;
    if (g >= 4 * NKC * 64) return;
    int lane = g & 63;
    int kc = (g >> 6) % NKC;
    int ct = g / (64 * NKC);
    int qd = lane >> 4, col = lane & 15;
    #pragma unroll
    for (int j = 0; j < 8; j++) {
        int k = kc * 32 + qd * 8 + j;
        float w = W[(size_t)k * 64 + ct * 16 + col];
        unsigned short h = f2bf(w);
        float rem = w - bf2f(h);
        Bhi[(size_t)g * 8 + j] = h;
        Blo[(size_t)g * 8 + j] = f2bf(rem);
    }
}

// ---------------- MFMA GEMM: XW = X[N,K] @ W[K,64] + fused logits ----------------
// Split-precision bf16 (r10): 3 MFMAs (AhBh+AlBh+AhBl) => ~16-bit mantissa.
// REGISTER-PRESSURE HISTORY: r3 clamp spill / r4 straight-line clustering spill /
// r5 sched_barrier useless / r6 dynamic loop = only reliable scope bound.
template <int K>
__global__ __launch_bounds__(256) void k_mfma(const float* __restrict__ X,
                                              const unsigned short* __restrict__ Bhi,
                                              const unsigned short* __restrict__ Blo,
                                              const float* __restrict__ a_s, const float* __restrict__ a_d,
                                              float* __restrict__ XW, float* __restrict__ Ssrc,
                                              float* __restrict__ Sdst, int N) {
    constexpr int NKC = K / 32;
    int t = threadIdx.x, lane = t & 63, wid = t >> 6;
    int mtile = blockIdx.x * 4 + wid;
    if (mtile * 16 >= N) return;
    int m0 = mtile * 16;
    int qd = lane >> 4, col = lane & 15;

    int rA = m0 + col;
    rA = rA < N ? rA : N - 1;
    const float* xrow = X + (size_t)rA * K + qd * 8;

    const short8* bh = (const short8*)Bhi;
    const short8* bl = (const short8*)Blo;

    f32x4 acc[4];
    #pragma unroll
    for (int ct = 0; ct < 4; ct++) acc[ct] = (f32x4){0.f, 0.f, 0.f, 0.f};

    #pragma clang loop unroll(disable)
    for (int kc = 0; kc < NKC; kc++) {
        const float* xp = xrow + kc * 32;
        float4 xa = *(const float4*)xp;
        float4 xb = *(const float4*)(xp + 4);
        float xv[8] = {xa.x, xa.y, xa.z, xa.w, xb.x, xb.y, xb.z, xb.w};
        short8 ah, al;
        #pragma unroll
        for (int j = 0; j < 8; j++) {
            unsigned short h = f2bf(xv[j]);
            ah[j] = (short)h;
            al[j] = (short)f2bf(xv[j] - bf2f(h));
        }
        #pragma unroll
        for (int ct = 0; ct < 4; ct++) {
            short8 wh = bh[(ct * NKC + kc) * 64 + lane];
            short8 wl = bl[(ct * NKC + kc) * 64 + lane];
            acc[ct] = __builtin_amdgcn_mfma_f32_16x16x32_bf16(ah, wh, acc[ct], 0, 0, 0);
            acc[ct] = __builtin_amdgcn_mfma_f32_16x16x32_bf16(al, wh, acc[ct], 0, 0, 0);
            acc[ct] = __builtin_amdgcn_mfma_f32_16x16x32_bf16(ah, wl, acc[ct], 0, 0, 0);
        }
    }

    float asx[4], adx[4];
    #pragma unroll
    for (int ct = 0; ct < 4; ct++) {
        asx[ct] = a_s[ct * 16 + col];
        adx[ct] = a_d[ct * 16 + col];
    }
    #pragma unroll
    for (int r = 0; r < 4; r++) {
        int row = m0 + qd * 4 + r;
        if (row < N) {
            float vs = 0.f, vd = 0.f;
            #pragma unroll
            for (int ct = 0; ct < 4; ct++) {
                float v = acc[ct][r];
                XW[(size_t)row * 64 + ct * 16 + col] = v;
                vs += v * asx[ct];
                vd += v * adx[ct];
            }
            #pragma unroll
            for (int d = 1; d < 16; d <<= 1) {
                vs += __shfl_xor(vs, d);
                vd += __shfl_xor(vd, d);
            }
            if (col == 0) { Ssrc[row] = vs; Sdst[row] = vd; }
        }
    }
}

// ---------------- attention + aggregate: one wave per dst node ----------------
// r11 restructure: (1) per-lane weight precompute — one expf round + one
// xor-reduce replaces the serial per-edge expf/denom chain; (2) phase 2 uses
// lane=(edge-group g, feature-quad c): one float4 VMEM instr covers 4 edges
// (TA issue 16->4 cyc/edge, r9 lesson: same-address/wave loads cost ~16 cyc
// TA regardless of uniformity); group xor-reduce (16,32) at the end.
__global__ __launch_bounds__(256) void k_attn(const float* __restrict__ XW, const float* __restrict__ Ssrc,
                                              const float* __restrict__ Sdst, const int* __restrict__ csr,
                                              const int* __restrict__ off, const int* __restrict__ deg,
                                              const float* __restrict__ bias, float* __restrict__ H,
                                              int N, int do_relu) {
    int t = threadIdx.x, lane = t & 63, wid = t >> 6;
    int n = blockIdx.x * 4 + wid;
    if (n >= N) return;
    int g = lane >> 4, c = lane & 15;
    float sd = Sdst[n];
    int st = off[n], d = deg[n];

    // phase 1: gather logits for first 64 edges; wave max
    float eself = lrelu(Ssrc[n] + sd);
    float m = eself;
    int myS = 0;
    float myE = -1e30f;
    if (lane < d) {
        myS = csr[st + lane];
        myE = lrelu(Ssrc[myS] + sd);
        m = fmaxf(m, myE);
    }
    for (int i = 64 + lane; i < d; i += 64) {
        m = fmaxf(m, lrelu(Ssrc[csr[st + i]] + sd));
    }
    #pragma unroll
    for (int dd = 32; dd > 0; dd >>= 1) m = fmaxf(m, __shfl_xor(m, dd));

    // per-lane weights (zero-padded beyond deg) + wave-reduced denom
    float myW = (lane < d) ? __expf(myE - m) : 0.f;
    float wself = __expf(eself - m);
    float denom = myW;
    #pragma unroll
    for (int dd = 32; dd > 0; dd >>= 1) denom += __shfl_xor(denom, dd);
    denom += wself;  // wave-uniform

    // phase 2: 4 edges per round. lane loads float4 of edge (i+g)'s row.
    float4 acc4 = make_float4(0.f, 0.f, 0.f, 0.f);
    {
        float4 xs = *(const float4*)&XW[(size_t)n * 64 + c * 4];
        float w = (g == 0) ? wself : 0.f;
        acc4.x += w * xs.x; acc4.y += w * xs.y; acc4.z += w * xs.z; acc4.w += w * xs.w;
    }
    int dcap = d < 64 ? d : 64;
    for (int i = 0; i < dcap; i += 4) {
        int idx = i + g;                       // max 63 (i<=60, g<=3)
        int si = __shfl(myS, idx);
        float wi = __shfl(myW, idx);
        if (idx >= dcap) wi = 0.f;             // pad slots contribute 0
        const float4 xr = *(const float4*)&XW[(size_t)si * 64 + c * 4];
        acc4.x += wi * xr.x; acc4.y += wi * xr.y; acc4.z += wi * xr.z; acc4.w += wi * xr.w;
    }
    // rare tail (deg > 64): uniform serial
    for (int i = 64; i < d; i++) {
        int s = csr[st + i];
        float e = lrelu(Ssrc[s] + sd);
        float w = __expf(e - m);
        denom += w;
        float wt = (g == 0) ? w : 0.f;
        const float4 xr = *(const float4*)&XW[(size_t)s * 64 + c * 4];
        acc4.x += wt * xr.x; acc4.y += wt * xr.y; acc4.z += wt * xr.z; acc4.w += wt * xr.w;
    }

    // reduce across edge groups (lane xor 16, 32)
    #pragma unroll
    for (int mask = 16; mask <= 32; mask <<= 1) {
        acc4.x += __shfl_xor(acc4.x, mask);
        acc4.y += __shfl_xor(acc4.y, mask);
        acc4.z += __shfl_xor(acc4.z, mask);
        acc4.w += __shfl_xor(acc4.w, mask);
    }

    if (g == 0) {
        float4 b4 = *(const float4*)&bias[c * 4];
        float inv = 1.f / denom;
        float4 o;
        o.x = acc4.x * inv + b4.x;
        o.y = acc4.y * inv + b4.y;
        o.z = acc4.z * inv + b4.z;
        o.w = acc4.w * inv + b4.w;
        if (do_relu) {
            o.x = fmaxf(o.x, 0.f); o.y = fmaxf(o.y, 0.f);
            o.z = fmaxf(o.z, 0.f); o.w = fmaxf(o.w, 0.f);
        }
        *(float4*)&H[(size_t)n * 64 + c * 4] = o;
    }
}

// ---------------- head ----------------
__global__ __launch_bounds__(256) void k_head(const float* __restrict__ H, const int* __restrict__ ui,
                                              const int* __restrict__ mi, const float* __restrict__ fcW,
                                              const float* __restrict__ fcb, float* __restrict__ out, int B) {
    int t = threadIdx.x, lane = t & 63, wid = t >> 6;
    int i = blockIdx.x * 4 + wid;
    if (i >= B) return;
    int u = ui[i], m = mi[i];
    float v = H[(size_t)u * 64 + lane] * fcW[lane] + H[(size_t)m * 64 + lane] * fcW[64 + lane];
    #pragma unroll
    for (int dd = 32; dd > 0; dd >>= 1) v += __shfl_xor(v, dd);
    if (lane == 0) out[i] = v + fcb[0];
}

extern "C" void kernel_launch(void* const* d_in, const int* in_sizes, int n_in,
                              void* d_out, int out_size, void* d_ws, size_t ws_size,
                              hipStream_t stream) {
    const float* x   = (const float*)d_in[0];
    const int*   ei  = (const int*)d_in[1];
    const int*   ui  = (const int*)d_in[2];
    const int*   mi  = (const int*)d_in[3];
    const float* W1  = (const float*)d_in[4];
    const float* as1 = (const float*)d_in[5];
    const float* ad1 = (const float*)d_in[6];
    const float* b1  = (const float*)d_in[7];
    const float* W2  = (const float*)d_in[8];
    const float* as2 = (const float*)d_in[9];
    const float* ad2 = (const float*)d_in[10];
    const float* b2  = (const float*)d_in[11];
    const float* fcW = (const float*)d_in[12];
    const float* fcb = (const float*)d_in[13];
    float* out = (float*)d_out;

    const int Hdim = in_sizes[5];            // 64
    const int FIN  = in_sizes[4] / Hdim;     // 256
    const int N    = in_sizes[0] / FIN;      // 100000
    const int E    = in_sizes[1] / 2;        // 1000000
    const int B    = in_sizes[2];            // 16384

    char* w = (char*)d_ws;
    auto alloc = [&](size_t bytes) -> void* {
        void* p = (void*)w;
        w += (bytes + 255) & ~(size_t)255;
        return p;
    };
    float* xw   = (float*)alloc((size_t)N * 64 * 4);
    float* hbuf = (float*)alloc((size_t)N * 64 * 4);
    float* ssrc = (float*)alloc((size_t)N * 4);
    float* sdst = (float*)alloc((size_t)N * 4);
    int* degcur = (int*)alloc((size_t)2 * N * 4);
    int* deg = degcur;
    int* cur = degcur + N;
    int* offv  = (int*)alloc((size_t)N * 4);
    int* bsums = (int*)alloc((size_t)1024 * 4);
    int* csr   = (int*)alloc((size_t)E * 4);
    unsigned short* b1hi = (unsigned short*)alloc((size_t)4 * 8 * 64 * 8 * 2);
    unsigned short* b1lo = (unsigned short*)alloc((size_t)4 * 8 * 64 * 8 * 2);
    unsigned short* b2hi = (unsigned short*)alloc((size_t)4 * 2 * 64 * 8 * 2);
    unsigned short* b2lo = (unsigned short*)alloc((size_t)4 * 2 * 64 * 8 * 2);

    const int* esrc = ei;
    const int* edst = ei + E;

    // --- W pre-pack (independent of CSR) ---
    k_packW<256><<<8, 256, 0, stream>>>(W1, b1hi, b1lo);
    k_packW<64><<<2, 256, 0, stream>>>(W2, b2hi, b2lo);

    // --- build CSR by dst (shared by both layers) ---
    k_zero<<<(2 * N + 1023) / 1024, 1024, 0, stream>>>(degcur, 2 * N);
    k_hist<<<(E + 255) / 256, 256, 0, stream>>>(edst, deg, E);
    int nb = (N + 1023) / 1024;
    k_scan1<<<nb, 1024, 0, stream>>>(deg, offv, bsums, N);
    k_scan2<<<1, 1024, 0, stream>>>(bsums, nb);
    k_scan3<<<nb, 1024, 0, stream>>>(offv, bsums, N);
    k_scatter<<<(E + 255) / 256, 256, 0, stream>>>(esrc, edst, offv, cur, csr, E);

    const int mfmaBlocks = ((N + 15) / 16 + 3) / 4;

    // --- layer 1 ---
    k_mfma<256><<<mfmaBlocks, 256, 0, stream>>>(x, b1hi, b1lo, as1, ad1, xw, ssrc, sdst, N);
    k_attn<<<(N + 3) / 4, 256, 0, stream>>>(xw, ssrc, sdst, csr, offv, deg, b1, hbuf, N, 1);

    // --- layer 2 ---
    k_mfma<64><<<mfmaBlocks, 256, 0, stream>>>(hbuf, b2hi, b2lo, as2, ad2, xw, ssrc, sdst, N);
    k_attn<<<(N + 3) / 4, 256, 0, stream>>>(xw, ssrc, sdst, csr, offv, deg, b2, hbuf, N, 0);

    // --- head ---
    k_head<<<(B + 3) / 4, 256, 0, stream>>>(hbuf, ui, mi, fcW, fcb, out, B);
}

// Round 12
// 414.156 us; speedup vs baseline: 2.0331x; 1.0295x over previous
//
#include <hip/hip_runtime.h>
#include <hip/hip_bf16.h>
#include <hip/hip_fp16.h>

#define LRELU_SLOPE 0.2f

__device__ __forceinline__ float lrelu(float x) { return x > 0.f ? x : LRELU_SLOPE * x; }

typedef __attribute__((ext_vector_type(8))) short short8;
typedef __attribute__((ext_vector_type(4))) float f32x4;

__device__ __forceinline__ unsigned short f2bf(float f) {
    unsigned u = __builtin_bit_cast(unsigned, f);
    u = (u + 0x7FFFu + ((u >> 16) & 1u)) >> 16;  // RNE
    return (unsigned short)u;
}
__device__ __forceinline__ float bf2f(unsigned short b) {
    unsigned u = ((unsigned)b) << 16;
    return __builtin_bit_cast(float, u);
}

// ---------------- utility kernels ----------------
__global__ void k_zero(int* __restrict__ a, int n) {
    int i = blockIdx.x * blockDim.x + threadIdx.x;
    if (i < n) a[i] = 0;
}

__global__ void k_hist(const int* __restrict__ dst, int* __restrict__ deg, int E) {
    int i = blockIdx.x * blockDim.x + threadIdx.x;
    if (i < E) atomicAdd(&deg[dst[i]], 1);
}

__global__ __launch_bounds__(1024) void k_scan1(const int* __restrict__ deg, int* __restrict__ off,
                                                int* __restrict__ bsums, int N) {
    int t = threadIdx.x, b = blockIdx.x;
    int idx = b * 1024 + t;
    int v = (idx < N) ? deg[idx] : 0;
    int lane = t & 63, wid = t >> 6;
    int incl = v;
    #pragma unroll
    for (int d = 1; d < 64; d <<= 1) {
        int u = __shfl_up(incl, d);
        if (lane >= d) incl += u;
    }
    __shared__ int ws[16];
    if (lane == 63) ws[wid] = incl;
    __syncthreads();
    if (wid == 0) {
        int wv = (lane < 16) ? ws[lane] : 0;
        #pragma unroll
        for (int d = 1; d < 16; d <<= 1) {
            int u = __shfl_up(wv, d);
            if (lane >= d) wv += u;
        }
        if (lane < 16) ws[lane] = wv;
    }
    __syncthreads();
    int woff = (wid > 0) ? ws[wid - 1] : 0;
    if (idx < N) off[idx] = woff + incl - v;
    if (t == 0) bsums[b] = ws[15];
}

__global__ __launch_bounds__(1024) void k_scan2(int* __restrict__ bs, int nb) {
    __shared__ int s[1024];
    int t = threadIdx.x;
    s[t] = (t < nb) ? bs[t] : 0;
    __syncthreads();
    for (int d = 1; d < 1024; d <<= 1) {
        int v = (t >= d) ? s[t - d] : 0;
        __syncthreads();
        s[t] += v;
        __syncthreads();
    }
    if (t < nb) bs[t] = t ? s[t - 1] : 0;
}

__global__ __launch_bounds__(1024) void k_scan3(int* __restrict__ off, const int* __restrict__ bs, int N) {
    int i = blockIdx.x * 1024 + threadIdx.x;
    if (i < N) off[i] += bs[blockIdx.x];
}

__global__ void k_scatter(const int* __restrict__ src, const int* __restrict__ dst,
                          const int* __restrict__ off, int* __restrict__ cur,
                          int* __restrict__ csr, int E) {
    int i = blockIdx.x * blockDim.x + threadIdx.x;
    if (i < E) {
        int d = dst[i];
        int pos = off[d] + atomicAdd(&cur[d], 1);
        csr[pos] = src[i];
    }
}

// ---------------- W pre-pack: fp32 [K][64] -> B-fragment bf16 hi/lo ----------------
template <int K>
__global__ __launch_bounds__(256) void k_packW(const float* __restrict__ W,
                                               unsigned short* __restrict__ Bhi,
                                               unsigned short* __restrict__ Blo) {
    constexpr int NKC = K / 32;
    int g = blockIdx.x * 256 + threadIdx.x;
    if (g >= 4 * NKC * 64) return;
    int lane = g & 63;
    int kc = (g >> 6) % NKC;
    int ct = g / (64 * NKC);
    int qd = lane >> 4, col = lane & 15;
    #pragma unroll
    for (int j = 0; j < 8; j++) {
        int k = kc * 32 + qd * 8 + j;
        float w = W[(size_t)k * 64 + ct * 16 + col];
        unsigned short h = f2bf(w);
        float rem = w - bf2f(h);
        Bhi[(size_t)g * 8 + j] = h;
        Blo[(size_t)g * 8 + j] = f2bf(rem);
    }
}

// ---------------- MFMA GEMM: XW(fp16) = X[N,K] @ W[K,64] + fused logits ----------------
// Split-precision bf16 (r10): 3 MFMAs (AhBh+AlBh+AhBl) => ~16-bit mantissa.
// r12: XW stored as fp16 — its ONLY consumer is the attention gather; fp16
// halves the gather's cache-line footprint (the r11 lesson: gather cost =
// unique 64B lines per instr, not bytes). Logits from fp32 acc (pre-rounding).
// REGISTER-PRESSURE HISTORY: r3 clamp spill / r4 straight-line clustering spill /
// r5 sched_barrier useless / r6 dynamic loop = only reliable scope bound.
template <int K>
__global__ __launch_bounds__(256) void k_mfma(const float* __restrict__ X,
                                              const unsigned short* __restrict__ Bhi,
                                              const unsigned short* __restrict__ Blo,
                                              const float* __restrict__ a_s, const float* __restrict__ a_d,
                                              __half* __restrict__ XW, float* __restrict__ Ssrc,
                                              float* __restrict__ Sdst, int N) {
    constexpr int NKC = K / 32;
    int t = threadIdx.x, lane = t & 63, wid = t >> 6;
    int mtile = blockIdx.x * 4 + wid;
    if (mtile * 16 >= N) return;
    int m0 = mtile * 16;
    int qd = lane >> 4, col = lane & 15;

    int rA = m0 + col;
    rA = rA < N ? rA : N - 1;
    const float* xrow = X + (size_t)rA * K + qd * 8;

    const short8* bh = (const short8*)Bhi;
    const short8* bl = (const short8*)Blo;

    f32x4 acc[4];
    #pragma unroll
    for (int ct = 0; ct < 4; ct++) acc[ct] = (f32x4){0.f, 0.f, 0.f, 0.f};

    #pragma clang loop unroll(disable)
    for (int kc = 0; kc < NKC; kc++) {
        const float* xp = xrow + kc * 32;
        float4 xa = *(const float4*)xp;
        float4 xb = *(const float4*)(xp + 4);
        float xv[8] = {xa.x, xa.y, xa.z, xa.w, xb.x, xb.y, xb.z, xb.w};
        short8 ah, al;
        #pragma unroll
        for (int j = 0; j < 8; j++) {
            unsigned short h = f2bf(xv[j]);
            ah[j] = (short)h;
            al[j] = (short)f2bf(xv[j] - bf2f(h));
        }
        #pragma unroll
        for (int ct = 0; ct < 4; ct++) {
            short8 wh = bh[(ct * NKC + kc) * 64 + lane];
            short8 wl = bl[(ct * NKC + kc) * 64 + lane];
            acc[ct] = __builtin_amdgcn_mfma_f32_16x16x32_bf16(ah, wh, acc[ct], 0, 0, 0);
            acc[ct] = __builtin_amdgcn_mfma_f32_16x16x32_bf16(al, wh, acc[ct], 0, 0, 0);
            acc[ct] = __builtin_amdgcn_mfma_f32_16x16x32_bf16(ah, wl, acc[ct], 0, 0, 0);
        }
    }

    float asx[4], adx[4];
    #pragma unroll
    for (int ct = 0; ct < 4; ct++) {
        asx[ct] = a_s[ct * 16 + col];
        adx[ct] = a_d[ct * 16 + col];
    }
    #pragma unroll
    for (int r = 0; r < 4; r++) {
        int row = m0 + qd * 4 + r;
        if (row < N) {
            float vs = 0.f, vd = 0.f;
            #pragma unroll
            for (int ct = 0; ct < 4; ct++) {
                float v = acc[ct][r];
                XW[(size_t)row * 64 + ct * 16 + col] = __float2half(v);
                vs += v * asx[ct];
                vd += v * adx[ct];
            }
            #pragma unroll
            for (int d = 1; d < 16; d <<= 1) {
                vs += __shfl_xor(vs, d);
                vd += __shfl_xor(vd, d);
            }
            if (col == 0) { Ssrc[row] = vs; Sdst[row] = vd; }
        }
    }
}

// ---------------- attention + aggregate: one wave per dst node ----------------
// r11 structure (per-lane weight precompute + 4-edge-group gather) with r12
// fp16 XW: lane (g=edge slot, c=feature quad) loads half4 (8B) of edge g's
// row -> 4 edges per VMEM instr at 2 lines/edge (was 4). fp32 accumulate.
__global__ __launch_bounds__(256) void k_attn(const __half* __restrict__ XW, const float* __restrict__ Ssrc,
                                              const float* __restrict__ Sdst, const int* __restrict__ csr,
                                              const int* __restrict__ off, const int* __restrict__ deg,
                                              const float* __restrict__ bias, float* __restrict__ H,
                                              int N, int do_relu) {
    int t = threadIdx.x, lane = t & 63, wid = t >> 6;
    int n = blockIdx.x * 4 + wid;
    if (n >= N) return;
    int g = lane >> 4, c = lane & 15;
    float sd = Sdst[n];
    int st = off[n], d = deg[n];

    // phase 1: gather logits for first 64 edges; wave max
    float eself = lrelu(Ssrc[n] + sd);
    float m = eself;
    int myS = 0;
    float myE = -1e30f;
    if (lane < d) {
        myS = csr[st + lane];
        myE = lrelu(Ssrc[myS] + sd);
        m = fmaxf(m, myE);
    }
    for (int i = 64 + lane; i < d; i += 64) {
        m = fmaxf(m, lrelu(Ssrc[csr[st + i]] + sd));
    }
    #pragma unroll
    for (int dd = 32; dd > 0; dd >>= 1) m = fmaxf(m, __shfl_xor(m, dd));

    // per-lane weights (zero-padded beyond deg) + wave-reduced denom
    float myW = (lane < d) ? __expf(myE - m) : 0.f;
    float wself = __expf(eself - m);
    float denom = myW;
    #pragma unroll
    for (int dd = 32; dd > 0; dd >>= 1) denom += __shfl_xor(denom, dd);
    denom += wself;  // wave-uniform

    auto gat = [&](int row, float w, float4& a4) {
        float2 raw = *(const float2*)(XW + (size_t)row * 64 + c * 4);
        const __half2* hp = (const __half2*)&raw;
        float2 f0 = __half22float2(hp[0]);
        float2 f1 = __half22float2(hp[1]);
        a4.x += w * f0.x; a4.y += w * f0.y; a4.z += w * f1.x; a4.w += w * f1.y;
    };

    // phase 2: 4 edges per round. lane loads half4 of edge (i+g)'s row.
    float4 acc4 = make_float4(0.f, 0.f, 0.f, 0.f);
    gat(n, (g == 0) ? wself : 0.f, acc4);
    int dcap = d < 64 ? d : 64;
    for (int i = 0; i < dcap; i += 4) {
        int idx = i + g;                       // max 63 (i<=60, g<=3)
        int si = __shfl(myS, idx);
        float wi = __shfl(myW, idx);
        if (idx >= dcap) wi = 0.f;             // pad slots contribute 0
        gat(si, wi, acc4);
    }
    // rare tail (deg > 64): uniform serial
    for (int i = 64; i < d; i++) {
        int s = csr[st + i];
        float e = lrelu(Ssrc[s] + sd);
        float w = __expf(e - m);
        denom += w;
        gat(s, (g == 0) ? w : 0.f, acc4);
    }

    // reduce across edge groups (lane xor 16, 32)
    #pragma unroll
    for (int mask = 16; mask <= 32; mask <<= 1) {
        acc4.x += __shfl_xor(acc4.x, mask);
        acc4.y += __shfl_xor(acc4.y, mask);
        acc4.z += __shfl_xor(acc4.z, mask);
        acc4.w += __shfl_xor(acc4.w, mask);
    }

    if (g == 0) {
        float4 b4 = *(const float4*)&bias[c * 4];
        float inv = 1.f / denom;
        float4 o;
        o.x = acc4.x * inv + b4.x;
        o.y = acc4.y * inv + b4.y;
        o.z = acc4.z * inv + b4.z;
        o.w = acc4.w * inv + b4.w;
        if (do_relu) {
            o.x = fmaxf(o.x, 0.f); o.y = fmaxf(o.y, 0.f);
            o.z = fmaxf(o.z, 0.f); o.w = fmaxf(o.w, 0.f);
        }
        *(float4*)&H[(size_t)n * 64 + c * 4] = o;
    }
}

// ---------------- head ----------------
__global__ __launch_bounds__(256) void k_head(const float* __restrict__ H, const int* __restrict__ ui,
                                              const int* __restrict__ mi, const float* __restrict__ fcW,
                                              const float* __restrict__ fcb, float* __restrict__ out, int B) {
    int t = threadIdx.x, lane = t & 63, wid = t >> 6;
    int i = blockIdx.x * 4 + wid;
    if (i >= B) return;
    int u = ui[i], m = mi[i];
    float v = H[(size_t)u * 64 + lane] * fcW[lane] + H[(size_t)m * 64 + lane] * fcW[64 + lane];
    #pragma unroll
    for (int dd = 32; dd > 0; dd >>= 1) v += __shfl_xor(v, dd);
    if (lane == 0) out[i] = v + fcb[0];
}

extern "C" void kernel_launch(void* const* d_in, const int* in_sizes, int n_in,
                              void* d_out, int out_size, void* d_ws, size_t ws_size,
                              hipStream_t stream) {
    const float* x   = (const float*)d_in[0];
    const int*   ei  = (const int*)d_in[1];
    const int*   ui  = (const int*)d_in[2];
    const int*   mi  = (const int*)d_in[3];
    const float* W1  = (const float*)d_in[4];
    const float* as1 = (const float*)d_in[5];
    const float* ad1 = (const float*)d_in[6];
    const float* b1  = (const float*)d_in[7];
    const float* W2  = (const float*)d_in[8];
    const float* as2 = (const float*)d_in[9];
    const float* ad2 = (const float*)d_in[10];
    const float* b2  = (const float*)d_in[11];
    const float* fcW = (const float*)d_in[12];
    const float* fcb = (const float*)d_in[13];
    float* out = (float*)d_out;

    const int Hdim = in_sizes[5];            // 64
    const int FIN  = in_sizes[4] / Hdim;     // 256
    const int N    = in_sizes[0] / FIN;      // 100000
    const int E    = in_sizes[1] / 2;        // 1000000
    const int B    = in_sizes[2];            // 16384

    char* w = (char*)d_ws;
    auto alloc = [&](size_t bytes) -> void* {
        void* p = (void*)w;
        w += (bytes + 255) & ~(size_t)255;
        return p;
    };
    __half* xw  = (__half*)alloc((size_t)N * 64 * 2);
    float* hbuf = (float*)alloc((size_t)N * 64 * 4);
    float* ssrc = (float*)alloc((size_t)N * 4);
    float* sdst = (float*)alloc((size_t)N * 4);
    int* degcur = (int*)alloc((size_t)2 * N * 4);
    int* deg = degcur;
    int* cur = degcur + N;
    int* offv  = (int*)alloc((size_t)N * 4);
    int* bsums = (int*)alloc((size_t)1024 * 4);
    int* csr   = (int*)alloc((size_t)E * 4);
    unsigned short* b1hi = (unsigned short*)alloc((size_t)4 * 8 * 64 * 8 * 2);
    unsigned short* b1lo = (unsigned short*)alloc((size_t)4 * 8 * 64 * 8 * 2);
    unsigned short* b2hi = (unsigned short*)alloc((size_t)4 * 2 * 64 * 8 * 2);
    unsigned short* b2lo = (unsigned short*)alloc((size_t)4 * 2 * 64 * 8 * 2);

    const int* esrc = ei;
    const int* edst = ei + E;

    // --- W pre-pack (independent of CSR) ---
    k_packW<256><<<8, 256, 0, stream>>>(W1, b1hi, b1lo);
    k_packW<64><<<2, 256, 0, stream>>>(W2, b2hi, b2lo);

    // --- build CSR by dst (shared by both layers) ---
    k_zero<<<(2 * N + 1023) / 1024, 1024, 0, stream>>>(degcur, 2 * N);
    k_hist<<<(E + 255) / 256, 256, 0, stream>>>(edst, deg, E);
    int nb = (N + 1023) / 1024;
    k_scan1<<<nb, 1024, 0, stream>>>(deg, offv, bsums, N);
    k_scan2<<<1, 1024, 0, stream>>>(bsums, nb);
    k_scan3<<<nb, 1024, 0, stream>>>(offv, bsums, N);
    k_scatter<<<(E + 255) / 256, 256, 0, stream>>>(esrc, edst, offv, cur, csr, E);

    const int mfmaBlocks = ((N + 15) / 16 + 3) / 4;

    // --- layer 1 ---
    k_mfma<256><<<mfmaBlocks, 256, 0, stream>>>(x, b1hi, b1lo, as1, ad1, xw, ssrc, sdst, N);
    k_attn<<<(N + 3) / 4, 256, 0, stream>>>(xw, ssrc, sdst, csr, offv, deg, b1, hbuf, N, 1);

    // --- layer 2 ---
    k_mfma<64><<<mfmaBlocks, 256, 0, stream>>>(hbuf, b2hi, b2lo, as2, ad2, xw, ssrc, sdst, N);
    k_attn<<<(N + 3) / 4, 256, 0, stream>>>(xw, ssrc, sdst, csr, offv, deg, b2, hbuf, N, 0);

    // --- head ---
    k_head<<<(B + 3) / 4, 256, 0, stream>>>(hbuf, ui, mi, fcW, fcb, out, B);
}